// Round 1
// baseline (1521.559 us; speedup 1.0000x reference)
//
#include <hip/hip_runtime.h>
#include <cmath>

constexpr int kB  = 8;
constexpr int kC  = 256;
constexpr int kCQ = 32;
constexpr int kN  = 4096;

// ---------------------------------------------------------------------------
// Projection kernel: 1x1 convs as channel matmuls.
// grid (16, 8, 6), block 256. z=0..3: V e-block z ; z=4: Q ; z=5: K
// Thread owns one n (coalesced x loads); weights read wave-uniform -> s_load.
// ---------------------------------------------------------------------------
__global__ __launch_bounds__(256) void proj_kernel(
    const float* __restrict__ x,
    const float* __restrict__ wq, const float* __restrict__ bq,
    const float* __restrict__ wk, const float* __restrict__ bk,
    const float* __restrict__ wv, const float* __restrict__ bv,
    float* __restrict__ Qn, float* __restrict__ Kn, float* __restrict__ Vt)
{
    const int t = threadIdx.x;
    const int b = blockIdx.y;
    const int z = blockIdx.z;
    const int n = blockIdx.x * 256 + t;
    const float* xb = x + ((size_t)b * kC) * kN + n;

    if (z < 4) {
        const int eb = z;
        float acc[64];
#pragma unroll
        for (int j = 0; j < 64; ++j) acc[j] = bv[eb * 64 + j];
        for (int cc = 0; cc < kC; cc += 32) {
            float xv[32];
#pragma unroll
            for (int i = 0; i < 32; ++i) xv[i] = xb[(size_t)(cc + i) * kN];
#pragma unroll 2
            for (int e2 = 0; e2 < 64; ++e2) {
                const float4* wrow = (const float4*)(wv + (size_t)(eb * 64 + e2) * kC + cc);
                float s = 0.f;
#pragma unroll
                for (int c4 = 0; c4 < 8; ++c4) {
                    float4 w4 = wrow[c4];
                    s += xv[c4*4+0]*w4.x + xv[c4*4+1]*w4.y
                       + xv[c4*4+2]*w4.z + xv[c4*4+3]*w4.w;
                }
                acc[e2] += s;
            }
        }
        float4* dst = (float4*)(Vt + ((size_t)b * kN + n) * kC + eb * 64);
#pragma unroll
        for (int j4 = 0; j4 < 16; ++j4)
            dst[j4] = make_float4(acc[j4*4], acc[j4*4+1], acc[j4*4+2], acc[j4*4+3]);
    } else {
        const float* w    = (z == 4) ? wq : wk;
        const float* bias = (z == 4) ? bq : bk;
        float* outp       = (z == 4) ? Qn : Kn;
        float acc[32];
#pragma unroll
        for (int j = 0; j < 32; ++j) acc[j] = bias[j];
        for (int cc = 0; cc < kC; cc += 32) {
            float xv[32];
#pragma unroll
            for (int i = 0; i < 32; ++i) xv[i] = xb[(size_t)(cc + i) * kN];
#pragma unroll 2
            for (int e2 = 0; e2 < 32; ++e2) {
                const float4* wrow = (const float4*)(w + (size_t)e2 * kC + cc);
                float s = 0.f;
#pragma unroll
                for (int c4 = 0; c4 < 8; ++c4) {
                    float4 w4 = wrow[c4];
                    s += xv[c4*4+0]*w4.x + xv[c4*4+1]*w4.y
                       + xv[c4*4+2]*w4.z + xv[c4*4+3]*w4.w;
                }
                acc[e2] += s;
            }
        }
        float4* dst = (float4*)(outp + ((size_t)b * kN + n) * kCQ);
#pragma unroll
        for (int j4 = 0; j4 < 8; ++j4)
            dst[j4] = make_float4(acc[j4*4], acc[j4*4+1], acc[j4*4+2], acc[j4*4+3]);
    }
}

// ---------------------------------------------------------------------------
// Flash attention (fp32): grid (64, 8), block 256.
// BQ=64 queries per block, BM=32 keys per tile.
// Thread (qg=t/16, mg=t%15..) owns query rows qi=qg*4+r in BOTH phases, so
// online-softmax state stays in registers; reductions are shfl over the 16
// lanes sharing qg; p_s rows are wave-private (no barrier score->PV).
// LDS ~54 KB -> 2 blocks/CU.
// ---------------------------------------------------------------------------
__global__ __launch_bounds__(256) void attn_kernel(
    const float* __restrict__ Qn, const float* __restrict__ Kn,
    const float* __restrict__ Vt,
    const float* __restrict__ x, const float* __restrict__ gptr,
    float* __restrict__ out)
{
    __shared__ __align__(16) float q_s[64 * 36];  // stride 36: 2-way worst
    __shared__ __align__(16) float k_s[32 * 36];
    __shared__ __align__(16) float v_s[32 * 256];
    __shared__ __align__(16) float p_s[64 * 33];  // stride 33 breaks pow2

    const int t  = threadIdx.x;
    const int qb = blockIdx.x;
    const int b  = blockIdx.y;
    const int qg = t >> 4;   // 0..15 : query group (4 rows)
    const int mg = t & 15;   // 0..15 : key/channel group

    // load Q tile (64 x 32) -> q_s
    {
        const float4* src = (const float4*)(Qn + ((size_t)b * kN + (size_t)qb * 64) * kCQ);
#pragma unroll
        for (int i = 0; i < 2; ++i) {
            int f4 = i * 256 + t;
            int row = f4 >> 3, col4 = f4 & 7;
            *(float4*)&q_s[row * 36 + col4 * 4] = src[f4];
        }
    }

    float  m_i[4], l_i[4];
    float4 acc4[4][4];   // [row r][chan quad k], c = mg*4 + 64*k + i
#pragma unroll
    for (int r = 0; r < 4; ++r) {
        m_i[r] = -INFINITY; l_i[r] = 0.f;
#pragma unroll
        for (int k = 0; k < 4; ++k) acc4[r][k] = make_float4(0.f, 0.f, 0.f, 0.f);
    }

    for (int mb = 0; mb < kN / 32; ++mb) {
        __syncthreads();   // previous PV done with v_s
        {
            const float4* ksrc = (const float4*)(Kn + ((size_t)b * kN + (size_t)mb * 32) * kCQ);
            int f4 = t;                      // 256 float4 = 32x32
            int row = f4 >> 3, col4 = f4 & 7;
            *(float4*)&k_s[row * 36 + col4 * 4] = ksrc[f4];
            const float4* vsrc = (const float4*)(Vt + ((size_t)b * kN + (size_t)mb * 32) * kC);
#pragma unroll
            for (int i = 0; i < 8; ++i) {
                int g4 = i * 256 + t;        // 2048 float4 = 32x256
                *(float4*)&v_s[g4 * 4] = vsrc[g4];
            }
        }
        __syncthreads();

        // ---- scores: s[r][s2] for qi=qg*4+r, mi = mg + 16*s2 ----
        float sc[4][2];
#pragma unroll
        for (int s2 = 0; s2 < 2; ++s2) {
            const int mi = mg + 16 * s2;
            float4 k4[8];
#pragma unroll
            for (int kq = 0; kq < 8; ++kq) k4[kq] = *(const float4*)&k_s[mi * 36 + kq * 4];
#pragma unroll
            for (int r = 0; r < 4; ++r) {
                const int qi = qg * 4 + r;
                float s = 0.f;
#pragma unroll
                for (int kq = 0; kq < 8; ++kq) {
                    float4 q4 = *(const float4*)&q_s[qi * 36 + kq * 4];
                    s += q4.x*k4[kq].x + q4.y*k4[kq].y + q4.z*k4[kq].z + q4.w*k4[kq].w;
                }
                sc[r][s2] = s;
            }
        }

        // ---- online softmax over the 16 lanes sharing qg ----
        float alpha[4];
#pragma unroll
        for (int r = 0; r < 4; ++r) {
            float mx = fmaxf(sc[r][0], sc[r][1]);
#pragma unroll
            for (int off = 1; off < 16; off <<= 1) mx = fmaxf(mx, __shfl_xor(mx, off));
            const float mnew = fmaxf(m_i[r], mx);
            float p0 = __expf(sc[r][0] - mnew);
            float p1 = __expf(sc[r][1] - mnew);
            float ls = p0 + p1;
#pragma unroll
            for (int off = 1; off < 16; off <<= 1) ls += __shfl_xor(ls, off);
            alpha[r] = __expf(m_i[r] - mnew);
            l_i[r]   = l_i[r] * alpha[r] + ls;
            m_i[r]   = mnew;
            p_s[(qg * 4 + r) * 33 + mg]      = p0;
            p_s[(qg * 4 + r) * 33 + mg + 16] = p1;
        }
        // no __syncthreads needed: p_s rows are written+read by the same wave

        // ---- PV accumulate ----
#pragma unroll
        for (int r = 0; r < 4; ++r) {
#pragma unroll
            for (int k = 0; k < 4; ++k) {
                acc4[r][k].x *= alpha[r]; acc4[r][k].y *= alpha[r];
                acc4[r][k].z *= alpha[r]; acc4[r][k].w *= alpha[r];
            }
        }
#pragma unroll 2
        for (int mi = 0; mi < 32; ++mi) {
            float4 v4[4];
#pragma unroll
            for (int k = 0; k < 4; ++k)
                v4[k] = *(const float4*)&v_s[mi * 256 + mg * 4 + 64 * k];
            float pr[4];
#pragma unroll
            for (int r = 0; r < 4; ++r) pr[r] = p_s[(qg * 4 + r) * 33 + mi];
#pragma unroll
            for (int r = 0; r < 4; ++r) {
#pragma unroll
                for (int k = 0; k < 4; ++k) {
                    acc4[r][k].x += pr[r] * v4[k].x;
                    acc4[r][k].y += pr[r] * v4[k].y;
                    acc4[r][k].z += pr[r] * v4[k].z;
                    acc4[r][k].w += pr[r] * v4[k].w;
                }
            }
        }
    }

    // ---- epilogue: out[b,c,n] = gamma * acc/l + x ----
    const float g = gptr[0];
#pragma unroll
    for (int r = 0; r < 4; ++r) {
        const int n = qb * 64 + qg * 4 + r;
        const float inv_l = 1.0f / l_i[r];
#pragma unroll
        for (int k = 0; k < 4; ++k) {
            const float vals[4] = {acc4[r][k].x, acc4[r][k].y, acc4[r][k].z, acc4[r][k].w};
#pragma unroll
            for (int i = 0; i < 4; ++i) {
                const int c = mg * 4 + 64 * k + i;
                const size_t idx = ((size_t)b * kC + c) * kN + n;
                out[idx] = g * (vals[i] * inv_l) + x[idx];
            }
        }
    }
}

extern "C" void kernel_launch(void* const* d_in, const int* in_sizes, int n_in,
                              void* d_out, int out_size, void* d_ws, size_t ws_size,
                              hipStream_t stream)
{
    const float* x  = (const float*)d_in[0];
    const float* wq = (const float*)d_in[1];
    const float* bq = (const float*)d_in[2];
    const float* wk = (const float*)d_in[3];
    const float* bk = (const float*)d_in[4];
    const float* wv = (const float*)d_in[5];
    const float* bv = (const float*)d_in[6];
    const float* gm = (const float*)d_in[7];
    float* out = (float*)d_out;

    float* ws = (float*)d_ws;
    float* Qn = ws;                                   // [8][4096][32]
    float* Kn = ws + (size_t)kB * kN * kCQ;           // [8][4096][32]
    float* Vt = ws + 2 * (size_t)kB * kN * kCQ;       // [8][4096][256]  (~40 MB total)

    proj_kernel<<<dim3(16, 8, 6), 256, 0, stream>>>(x, wq, bq, wk, bk, wv, bv, Qn, Kn, Vt);
    attn_kernel<<<dim3(64, 8), 256, 0, stream>>>(Qn, Kn, Vt, x, gm, out);
}

// Round 2
// 462.087 us; speedup vs baseline: 3.2928x; 3.2928x over previous
//
#include <hip/hip_runtime.h>
#include <cmath>

typedef __attribute__((ext_vector_type(8))) short  short8;   // 8 bf16 = 4 VGPRs
typedef __attribute__((ext_vector_type(4))) float  float4v;  // 4 fp32 acc

constexpr int kB  = 8;
constexpr int kC  = 256;
constexpr int kCQ = 32;
constexpr int kN  = 4096;
constexpr float kLog2e = 1.44269504088896340736f;

__device__ __forceinline__ ushort f2bf(float f) {   // fp32 -> bf16 RNE
    uint u = __float_as_uint(f);
    return (ushort)((u + 0x7fffu + ((u >> 16) & 1u)) >> 16);
}

// ---------------------------------------------------------------------------
// Projection: 1x1 convs, fp32 compute, bf16 outputs.
// Qn/Kn: [b][n][32] (n-major, frag-ready for MFMA B/A ops)
// Vc:    [b][c][n] (channel-major, frag-ready for PV A-op direct-from-global)
// grid (16, 8, 6), block 256. z=0..3: V 64-ch block ; z=4: Q ; z=5: K
// ---------------------------------------------------------------------------
__global__ __launch_bounds__(256) void proj_kernel(
    const float* __restrict__ x,
    const float* __restrict__ wq, const float* __restrict__ bq,
    const float* __restrict__ wk, const float* __restrict__ bk,
    const float* __restrict__ wv, const float* __restrict__ bv,
    ushort* __restrict__ Qn, ushort* __restrict__ Kn, ushort* __restrict__ Vc)
{
    const int t = threadIdx.x;
    const int b = blockIdx.y;
    const int z = blockIdx.z;
    const int n = blockIdx.x * 256 + t;
    const float* xb = x + ((size_t)b * kC) * kN + n;

    if (z < 4) {
        const int eb = z;
        float acc[64];
#pragma unroll
        for (int j = 0; j < 64; ++j) acc[j] = bv[eb * 64 + j];
        for (int cc = 0; cc < kC; cc += 32) {
            float xv[32];
#pragma unroll
            for (int i = 0; i < 32; ++i) xv[i] = xb[(size_t)(cc + i) * kN];
#pragma unroll 2
            for (int e2 = 0; e2 < 64; ++e2) {
                const float4* wrow = (const float4*)(wv + (size_t)(eb * 64 + e2) * kC + cc);
                float s = 0.f;
#pragma unroll
                for (int c4 = 0; c4 < 8; ++c4) {
                    float4 w4 = wrow[c4];
                    s += xv[c4*4+0]*w4.x + xv[c4*4+1]*w4.y
                       + xv[c4*4+2]*w4.z + xv[c4*4+3]*w4.w;
                }
                acc[e2] += s;
            }
        }
        const size_t cb = (size_t)b * kC + eb * 64;
#pragma unroll 8
        for (int e = 0; e < 64; ++e)
            Vc[(cb + e) * kN + n] = f2bf(acc[e]);   // coalesced across lanes
    } else {
        const float* w    = (z == 4) ? wq : wk;
        const float* bias = (z == 4) ? bq : bk;
        ushort* outp      = (z == 4) ? Qn : Kn;
        float acc[32];
#pragma unroll
        for (int j = 0; j < 32; ++j) acc[j] = bias[j];
        for (int cc = 0; cc < kC; cc += 32) {
            float xv[32];
#pragma unroll
            for (int i = 0; i < 32; ++i) xv[i] = xb[(size_t)(cc + i) * kN];
#pragma unroll 2
            for (int e2 = 0; e2 < 32; ++e2) {
                const float4* wrow = (const float4*)(w + (size_t)e2 * kC + cc);
                float s = 0.f;
#pragma unroll
                for (int c4 = 0; c4 < 8; ++c4) {
                    float4 w4 = wrow[c4];
                    s += xv[c4*4+0]*w4.x + xv[c4*4+1]*w4.y
                       + xv[c4*4+2]*w4.z + xv[c4*4+3]*w4.w;
                }
                acc[e2] += s;
            }
        }
        uint pk[16];
#pragma unroll
        for (int j = 0; j < 16; ++j)
            pk[j] = (uint)f2bf(acc[2*j]) | ((uint)f2bf(acc[2*j+1]) << 16);
        uint4* dst = (uint4*)(outp + ((size_t)b * kN + n) * kCQ);
#pragma unroll
        for (int j4 = 0; j4 < 4; ++j4)
            dst[j4] = make_uint4(pk[j4*4], pk[j4*4+1], pk[j4*4+2], pk[j4*4+3]);
    }
}

// ---------------------------------------------------------------------------
// MFMA flash attention. grid (8 batch, 64 qblock), block 256 (4 waves).
// BQ=64 queries/block, BM=64 keys/tile.
//   S-phase:  S^T = K·Q^T  (M=key). Wave w owns queries w*16..w*16+15.
//             C-layout: col=lane&15 = q  -> softmax is in-lane + 2 shfl;
//             reg quad = 4 consecutive keys -> P packs to 8B LDS writes.
//   PV-phase: O^T = V^T·P^T (M=channel). Wave w owns channels w*64..w*64+63,
//             all 64 q. V^T A-frags load 16B direct from global (L2-resident,
//             XCD-affine). P^T B-frags via ds_read_b128 from p_s (stride 72).
// ---------------------------------------------------------------------------
__global__ __launch_bounds__(256, 2) void attn_kernel(
    const ushort* __restrict__ Qn, const ushort* __restrict__ Kn,
    const ushort* __restrict__ Vc,
    const float* __restrict__ x, const float* __restrict__ gptr,
    float* __restrict__ out)
{
    __shared__ __align__(16) ushort p_s[64 * 72];
    __shared__ float al_s[64];
    __shared__ float li_s[64];

    const int t    = threadIdx.x;
    const int b    = blockIdx.x;   // batch on x -> XCD affinity for V in L2
    const int qb   = blockIdx.y;
    const int wq   = t >> 6;       // wave 0..3
    const int lane = t & 63;
    const int col  = lane & 15;
    const int quad = lane >> 4;
    const int cw   = wq * 64;      // PV channel base for this wave

    // Q B-fragment, loaded once: B[k=d][n=q], q = qb*64 + wq*16 + col
    const short8 qfrag = *(const short8*)(
        Qn + ((size_t)b * kN + qb * 64 + wq * 16 + col) * kCQ + quad * 8);

    float4v acc[4][4];   // [mt: channel][nt: query]
#pragma unroll
    for (int mt = 0; mt < 4; ++mt)
#pragma unroll
        for (int nt = 0; nt < 4; ++nt) acc[mt][nt] = float4v{0.f, 0.f, 0.f, 0.f};

    float m_i = -INFINITY, l_i = 0.f;

    const ushort* Kb = Kn + (size_t)b * kN * kCQ;
    const ushort* Vb = Vc + ((size_t)b * kC + cw) * kN;
    const float4v zero4 = {0.f, 0.f, 0.f, 0.f};

    for (int tile = 0; tile < kN / 64; ++tile) {
        const int k0 = tile * 64;

        // ---- S^T = K · Q^T : 4 MFMAs ----
        float4v s[4];
#pragma unroll
        for (int mt = 0; mt < 4; ++mt) {
            short8 kf = *(const short8*)(
                Kb + (size_t)(k0 + mt * 16 + col) * kCQ + quad * 8);
            s[mt] = __builtin_amdgcn_mfma_f32_16x16x32_bf16(kf, qfrag, zero4, 0, 0, 0);
        }

        // ---- online softmax (base-2), q = col fixed per lane ----
        float mx = -INFINITY;
#pragma unroll
        for (int mt = 0; mt < 4; ++mt)
#pragma unroll
            for (int r = 0; r < 4; ++r) {
                float v = s[mt][r] * kLog2e;
                s[mt][r] = v;
                mx = fmaxf(mx, v);
            }
        mx = fmaxf(mx, __shfl_xor(mx, 16));
        mx = fmaxf(mx, __shfl_xor(mx, 32));
        const float mnew  = fmaxf(m_i, mx);
        const float alpha = exp2f(m_i - mnew);
        float lsum = 0.f;
#pragma unroll
        for (int mt = 0; mt < 4; ++mt) {
            float p0 = exp2f(s[mt][0] - mnew);
            float p1 = exp2f(s[mt][1] - mnew);
            float p2 = exp2f(s[mt][2] - mnew);
            float p3 = exp2f(s[mt][3] - mnew);
            lsum += (p0 + p1) + (p2 + p3);
            uint2 pk;
            pk.x = (uint)f2bf(p0) | ((uint)f2bf(p1) << 16);
            pk.y = (uint)f2bf(p2) | ((uint)f2bf(p3) << 16);
            // keys mt*16+quad*4 .. +3 contiguous at row q = wq*16+col
            *(uint2*)&p_s[(wq * 16 + col) * 72 + mt * 16 + quad * 4] = pk;
        }
        lsum += __shfl_xor(lsum, 16);
        lsum += __shfl_xor(lsum, 32);
        l_i = l_i * alpha + lsum;
        m_i = mnew;
        if (quad == 0) al_s[wq * 16 + col] = alpha;
        __syncthreads();   // P / alpha visible to all waves

        // ---- O^T = V^T · P^T : rescale + 32 MFMAs ----
        float al[4];
#pragma unroll
        for (int nt = 0; nt < 4; ++nt) al[nt] = al_s[nt * 16 + col];
#pragma unroll
        for (int mt = 0; mt < 4; ++mt)
#pragma unroll
            for (int nt = 0; nt < 4; ++nt) acc[mt][nt] *= al[nt];

#pragma unroll
        for (int ks = 0; ks < 2; ++ks) {
            short8 pf[4], vf[4];
#pragma unroll
            for (int nt = 0; nt < 4; ++nt)
                pf[nt] = *(const short8*)&p_s[(nt * 16 + col) * 72 + ks * 32 + quad * 8];
#pragma unroll
            for (int mt = 0; mt < 4; ++mt)
                vf[mt] = *(const short8*)(
                    Vb + (size_t)(mt * 16 + col) * kN + k0 + ks * 32 + quad * 8);
#pragma unroll
            for (int mt = 0; mt < 4; ++mt)
#pragma unroll
                for (int nt = 0; nt < 4; ++nt)
                    acc[mt][nt] = __builtin_amdgcn_mfma_f32_16x16x32_bf16(
                        vf[mt], pf[nt], acc[mt][nt], 0, 0, 0);
        }
        __syncthreads();   // PV done before next tile's P writes
    }

    // ---- epilogue: out = gamma * O/l + x ----
    if (quad == 0) li_s[wq * 16 + col] = l_i;
    __syncthreads();
    const float g = gptr[0];
    float linv[4];
#pragma unroll
    for (int nt = 0; nt < 4; ++nt) linv[nt] = 1.0f / li_s[nt * 16 + col];

#pragma unroll
    for (int mt = 0; mt < 4; ++mt) {
#pragma unroll
        for (int nt = 0; nt < 4; ++nt) {
            const int n = qb * 64 + nt * 16 + col;
#pragma unroll
            for (int r = 0; r < 4; ++r) {
                const int c = cw + mt * 16 + quad * 4 + r;
                const size_t idx = ((size_t)b * kC + c) * kN + n;
                out[idx] = g * (acc[mt][nt][r] * linv[nt]) + x[idx];
            }
        }
    }
}

extern "C" void kernel_launch(void* const* d_in, const int* in_sizes, int n_in,
                              void* d_out, int out_size, void* d_ws, size_t ws_size,
                              hipStream_t stream)
{
    const float* x  = (const float*)d_in[0];
    const float* wq = (const float*)d_in[1];
    const float* bq = (const float*)d_in[2];
    const float* wk = (const float*)d_in[3];
    const float* bk = (const float*)d_in[4];
    const float* wv = (const float*)d_in[5];
    const float* bv = (const float*)d_in[6];
    const float* gm = (const float*)d_in[7];
    float* out = (float*)d_out;

    ushort* Qn = (ushort*)d_ws;                       // [8][4096][32] bf16, 2 MB
    ushort* Kn = Qn + (size_t)kB * kN * kCQ;          // [8][4096][32] bf16, 2 MB
    ushort* Vc = Kn + (size_t)kB * kN * kCQ;          // [8][256][4096] bf16, 16 MB

    proj_kernel<<<dim3(16, 8, 6), 256, 0, stream>>>(x, wq, bq, wk, bk, wv, bv, Qn, Kn, Vc);
    attn_kernel<<<dim3(8, 64), 256, 0, stream>>>(Qn, Kn, Vc, x, gm, out);
}

// Round 3
// 409.774 us; speedup vs baseline: 3.7132x; 1.1277x over previous
//
#include <hip/hip_runtime.h>
#include <cmath>

typedef __attribute__((ext_vector_type(8))) short  short8;   // 8 bf16 = 4 VGPRs
typedef __attribute__((ext_vector_type(4))) float  float4v;  // 4 fp32 acc

constexpr int kB  = 8;
constexpr int kC  = 256;
constexpr int kCQ = 32;
constexpr int kN  = 4096;
constexpr float kLog2e = 1.44269504088896340736f;

__device__ __forceinline__ ushort f2bf(float f) {   // fp32 -> bf16 RNE
    uint u = __float_as_uint(f);
    return (ushort)((u + 0x7fffu + ((u >> 16) & 1u)) >> 16);
}

// ---------------------------------------------------------------------------
// Projection: 1x1 convs, fp32 compute, bf16 outputs.
// Qn/Kn: [b][n][32] n-major (MFMA frag-ready); Q pre-scaled by log2e.
// Vc:    [b][c][n] channel-major (PV A-op direct-from-global)
// grid (16, 8, 6), block 256. z=0..3: V 64-ch block ; z=4: Q ; z=5: K
// e2 loops FULLY unrolled: acc[] must be register-resident (R2: partial
// unroll left acc runtime-indexed -> scratch spill -> 313 MB WRITE_SIZE).
// ---------------------------------------------------------------------------
__global__ __launch_bounds__(256) void proj_kernel(
    const float* __restrict__ x,
    const float* __restrict__ wq, const float* __restrict__ bq,
    const float* __restrict__ wk, const float* __restrict__ bk,
    const float* __restrict__ wv, const float* __restrict__ bv,
    ushort* __restrict__ Qn, ushort* __restrict__ Kn, ushort* __restrict__ Vc)
{
    const int t = threadIdx.x;
    const int b = blockIdx.y;
    const int z = blockIdx.z;
    const int n = blockIdx.x * 256 + t;
    const float* xb = x + ((size_t)b * kC) * kN + n;

    if (z < 4) {
        const int eb = z;
        float acc[64];
#pragma unroll
        for (int j = 0; j < 64; ++j) acc[j] = bv[eb * 64 + j];
        for (int cc = 0; cc < kC; cc += 32) {
            float xv[32];
#pragma unroll
            for (int i = 0; i < 32; ++i) xv[i] = xb[(size_t)(cc + i) * kN];
#pragma unroll
            for (int e2 = 0; e2 < 64; ++e2) {
                const float4* wrow = (const float4*)(wv + (size_t)(eb * 64 + e2) * kC + cc);
                float s = 0.f;
#pragma unroll
                for (int c4 = 0; c4 < 8; ++c4) {
                    float4 w4 = wrow[c4];
                    s += xv[c4*4+0]*w4.x + xv[c4*4+1]*w4.y
                       + xv[c4*4+2]*w4.z + xv[c4*4+3]*w4.w;
                }
                acc[e2] += s;
            }
        }
        const size_t cb = (size_t)b * kC + eb * 64;
#pragma unroll
        for (int e = 0; e < 64; ++e)
            Vc[(cb + e) * kN + n] = f2bf(acc[e]);   // coalesced across lanes
    } else {
        const bool isQ    = (z == 4);
        const float* w    = isQ ? wq : wk;
        const float* bias = isQ ? bq : bk;
        ushort* outp      = isQ ? Qn : Kn;
        float acc[32];
#pragma unroll
        for (int j = 0; j < 32; ++j) acc[j] = bias[j];
        for (int cc = 0; cc < kC; cc += 32) {
            float xv[32];
#pragma unroll
            for (int i = 0; i < 32; ++i) xv[i] = xb[(size_t)(cc + i) * kN];
#pragma unroll
            for (int e2 = 0; e2 < 32; ++e2) {
                const float4* wrow = (const float4*)(w + (size_t)e2 * kC + cc);
                float s = 0.f;
#pragma unroll
                for (int c4 = 0; c4 < 8; ++c4) {
                    float4 w4 = wrow[c4];
                    s += xv[c4*4+0]*w4.x + xv[c4*4+1]*w4.y
                       + xv[c4*4+2]*w4.z + xv[c4*4+3]*w4.w;
                }
                acc[e2] += s;
            }
        }
        const float qs = isQ ? kLog2e : 1.0f;   // fold log2e into Q
        uint pk[16];
#pragma unroll
        for (int j = 0; j < 16; ++j)
            pk[j] = (uint)f2bf(acc[2*j] * qs) | ((uint)f2bf(acc[2*j+1] * qs) << 16);
        uint4* dst = (uint4*)(outp + ((size_t)b * kN + n) * kCQ);
#pragma unroll
        for (int j4 = 0; j4 < 4; ++j4)
            dst[j4] = make_uint4(pk[j4*4], pk[j4*4+1], pk[j4*4+2], pk[j4*4+3]);
    }
}

// ---------------------------------------------------------------------------
// MFMA flash attention. grid (8 batch, 64 qblock), block 256 (4 waves).
//   S-phase:  S^T = K·Q^T  (M=key). Wave w owns queries w*16..w*16+15.
//   PV-phase: O^T = V^T·P^T (M=channel). Wave w owns channels w*64..+63.
// R3: K frags for tile+1 and V frags for this tile are issued right after
// the S-MFMAs, so their latency hides under the softmax VALU chain and the
// first barrier's vmcnt(0) drain. Scores arrive pre-scaled by log2e (in Q).
// ---------------------------------------------------------------------------
__global__ __launch_bounds__(256, 2) void attn_kernel(
    const ushort* __restrict__ Qn, const ushort* __restrict__ Kn,
    const ushort* __restrict__ Vc,
    const float* __restrict__ x, const float* __restrict__ gptr,
    float* __restrict__ out)
{
    __shared__ __align__(16) ushort p_s[64 * 72];
    __shared__ float al_s[64];
    __shared__ float li_s[64];

    const int t    = threadIdx.x;
    const int b    = blockIdx.x;   // batch on x -> XCD affinity for V in L2
    const int qb   = blockIdx.y;
    const int wq   = t >> 6;       // wave 0..3
    const int lane = t & 63;
    const int col  = lane & 15;
    const int quad = lane >> 4;
    const int cw   = wq * 64;      // PV channel base for this wave

    const short8 qfrag = *(const short8*)(
        Qn + ((size_t)b * kN + qb * 64 + wq * 16 + col) * kCQ + quad * 8);

    float4v acc[4][4];   // [mt: channel][nt: query]
#pragma unroll
    for (int mt = 0; mt < 4; ++mt)
#pragma unroll
        for (int nt = 0; nt < 4; ++nt) acc[mt][nt] = float4v{0.f, 0.f, 0.f, 0.f};

    float m_i = -INFINITY, l_i = 0.f;

    const ushort* Kb = Kn + (size_t)b * kN * kCQ;
    const ushort* Vb = Vc + ((size_t)b * kC + cw) * kN;
    const float4v zero4 = {0.f, 0.f, 0.f, 0.f};

    // preload K frags for tile 0
    short8 kf[4];
#pragma unroll
    for (int mt = 0; mt < 4; ++mt)
        kf[mt] = *(const short8*)(Kb + (size_t)(mt * 16 + col) * kCQ + quad * 8);

    for (int tile = 0; tile < kN / 64; ++tile) {
        const int k0 = tile * 64;

        // ---- S^T = K · Q^T : 4 MFMAs (kf preloaded) ----
        float4v s[4];
#pragma unroll
        for (int mt = 0; mt < 4; ++mt)
            s[mt] = __builtin_amdgcn_mfma_f32_16x16x32_bf16(kf[mt], qfrag, zero4, 0, 0, 0);

        // ---- prefetch: V frags (this tile), K frags (next tile) ----
        short8 vf[2][4];
#pragma unroll
        for (int ks = 0; ks < 2; ++ks)
#pragma unroll
            for (int mt = 0; mt < 4; ++mt)
                vf[ks][mt] = *(const short8*)(
                    Vb + (size_t)(mt * 16 + col) * kN + k0 + ks * 32 + quad * 8);
        const int k0n = (tile + 1 < kN / 64) ? (tile + 1) * 64 : 0;
#pragma unroll
        for (int mt = 0; mt < 4; ++mt)
            kf[mt] = *(const short8*)(
                Kb + (size_t)(k0n + mt * 16 + col) * kCQ + quad * 8);

        // ---- online softmax (base 2; scores already *log2e) ----
        float mx = -INFINITY;
#pragma unroll
        for (int mt = 0; mt < 4; ++mt)
#pragma unroll
            for (int r = 0; r < 4; ++r) mx = fmaxf(mx, s[mt][r]);
        mx = fmaxf(mx, __shfl_xor(mx, 16));
        mx = fmaxf(mx, __shfl_xor(mx, 32));
        const float mnew  = fmaxf(m_i, mx);
        const float alpha = exp2f(m_i - mnew);
        float lsum = 0.f;
#pragma unroll
        for (int mt = 0; mt < 4; ++mt) {
            float p0 = exp2f(s[mt][0] - mnew);
            float p1 = exp2f(s[mt][1] - mnew);
            float p2 = exp2f(s[mt][2] - mnew);
            float p3 = exp2f(s[mt][3] - mnew);
            lsum += (p0 + p1) + (p2 + p3);
            uint2 pk;
            pk.x = (uint)f2bf(p0) | ((uint)f2bf(p1) << 16);
            pk.y = (uint)f2bf(p2) | ((uint)f2bf(p3) << 16);
            *(uint2*)&p_s[(wq * 16 + col) * 72 + mt * 16 + quad * 4] = pk;
        }
        lsum += __shfl_xor(lsum, 16);
        lsum += __shfl_xor(lsum, 32);
        l_i = l_i * alpha + lsum;
        m_i = mnew;
        if (quad == 0) al_s[wq * 16 + col] = alpha;
        __syncthreads();   // P/alpha visible; vf/kf drained by vmcnt(0) here

        // ---- O^T = V^T · P^T : rescale + 32 MFMAs ----
        float al[4];
#pragma unroll
        for (int nt = 0; nt < 4; ++nt) al[nt] = al_s[nt * 16 + col];
#pragma unroll
        for (int mt = 0; mt < 4; ++mt)
#pragma unroll
            for (int nt = 0; nt < 4; ++nt) acc[mt][nt] *= al[nt];

#pragma unroll
        for (int ks = 0; ks < 2; ++ks) {
            short8 pf[4];
#pragma unroll
            for (int nt = 0; nt < 4; ++nt)
                pf[nt] = *(const short8*)&p_s[(nt * 16 + col) * 72 + ks * 32 + quad * 8];
#pragma unroll
            for (int mt = 0; mt < 4; ++mt)
#pragma unroll
                for (int nt = 0; nt < 4; ++nt)
                    acc[mt][nt] = __builtin_amdgcn_mfma_f32_16x16x32_bf16(
                        vf[ks][mt], pf[nt], acc[mt][nt], 0, 0, 0);
        }
        __syncthreads();   // PV done before next tile's P writes
    }

    // ---- epilogue: out = gamma * O/l + x ----
    if (quad == 0) li_s[wq * 16 + col] = l_i;
    __syncthreads();
    const float g = gptr[0];
    float linv[4];
#pragma unroll
    for (int nt = 0; nt < 4; ++nt) linv[nt] = 1.0f / li_s[nt * 16 + col];

#pragma unroll
    for (int mt = 0; mt < 4; ++mt) {
#pragma unroll
        for (int nt = 0; nt < 4; ++nt) {
            const int n = qb * 64 + nt * 16 + col;
#pragma unroll
            for (int r = 0; r < 4; ++r) {
                const int c = cw + mt * 16 + quad * 4 + r;
                const size_t idx = ((size_t)b * kC + c) * kN + n;
                out[idx] = g * (acc[mt][nt][r] * linv[nt]) + x[idx];
            }
        }
    }
}

extern "C" void kernel_launch(void* const* d_in, const int* in_sizes, int n_in,
                              void* d_out, int out_size, void* d_ws, size_t ws_size,
                              hipStream_t stream)
{
    const float* x  = (const float*)d_in[0];
    const float* wq = (const float*)d_in[1];
    const float* bq = (const float*)d_in[2];
    const float* wk = (const float*)d_in[3];
    const float* bk = (const float*)d_in[4];
    const float* wv = (const float*)d_in[5];
    const float* bv = (const float*)d_in[6];
    const float* gm = (const float*)d_in[7];
    float* out = (float*)d_out;

    ushort* Qn = (ushort*)d_ws;                       // [8][4096][32] bf16, 2 MB
    ushort* Kn = Qn + (size_t)kB * kN * kCQ;          // [8][4096][32] bf16, 2 MB
    ushort* Vc = Kn + (size_t)kB * kN * kCQ;          // [8][256][4096] bf16, 16 MB

    proj_kernel<<<dim3(16, 8, 6), 256, 0, stream>>>(x, wq, bq, wk, bk, wv, bv, Qn, Kn, Vc);
    attn_kernel<<<dim3(8, 64), 256, 0, stream>>>(Qn, Kn, Vc, x, gm, out);
}

// Round 4
// 278.700 us; speedup vs baseline: 5.4595x; 1.4703x over previous
//
#include <hip/hip_runtime.h>
#include <cmath>

typedef __attribute__((ext_vector_type(8))) short  short8;   // 8 bf16 = 4 VGPRs
typedef __attribute__((ext_vector_type(4))) float  float4v;  // 4 fp32 acc

constexpr int kB  = 8;
constexpr int kC  = 256;
constexpr int kCQ = 32;
constexpr int kN  = 4096;
constexpr int kE  = 320;          // combined output rows: 256 V + 32 Q + 32 K
constexpr float kLog2e = 1.44269504088896340736f;

__device__ __forceinline__ ushort f2bf(float f) {   // fp32 -> bf16 RNE
    uint u = __float_as_uint(f);
    return (ushort)((u + 0x7fffu + ((u >> 16) & 1u)) >> 16);
}

// ---------------------------------------------------------------------------
// Prep: pack wv|wq*log2e|wk into Wb[320][256] bf16, biases into bb[320] f32.
// grid 320, block 256.
// ---------------------------------------------------------------------------
__global__ __launch_bounds__(256) void prep_kernel(
    const float* __restrict__ wq, const float* __restrict__ bq,
    const float* __restrict__ wk, const float* __restrict__ bk,
    const float* __restrict__ wv, const float* __restrict__ bv,
    ushort* __restrict__ Wb, float* __restrict__ bb)
{
    const int e = blockIdx.x;
    const int c = threadIdx.x;
    const float* src; float bsrc; float scale = 1.0f;
    if (e < 256)      { src = wv + (size_t)e * kC;        bsrc = bv[e]; }
    else if (e < 288) { src = wq + (size_t)(e-256) * kC;  bsrc = bq[e-256]; scale = kLog2e; }
    else              { src = wk + (size_t)(e-288) * kC;  bsrc = bk[e-288]; }
    Wb[(size_t)e * kC + c] = f2bf(src[c] * scale);
    if (c == 0) bb[e] = bsrc * scale;
}

// ---------------------------------------------------------------------------
// MFMA projection GEMM: D[e][n] = sum_c Wb[e][c] * x[b][c][n],  e in [0,320).
// grid (64 nblk, 8 batch), block 256 (4 waves).
// Wave w: e-half eh=w>>1 (160 rows = 10 m-tiles), n-half nh=w&1 (32 n = 2 nt).
// x tile (256c x 64n) staged to LDS TRANSPOSED as xF[n][c] bf16 (row 528B =
// 264 ushorts, +16B pad -> ds_read_b128 B-frags at conflict floor).
// Transpose done in-registers: each thread loads a 4x4 (c x n) block with 4
// coalesced float4 loads, repacks to 4 bf16x4 column writes (ds_write_b64).
// One barrier total; k-loop (8 iters) is barrier-free MFMA + L2-hot loads.
// R2 lesson: every loop touching acc[] is fully unrolled (no scratch).
// ---------------------------------------------------------------------------
__global__ __launch_bounds__(256) void proj_kernel(
    const float* __restrict__ x,
    const ushort* __restrict__ Wb, const float* __restrict__ bb,
    ushort* __restrict__ Qn, ushort* __restrict__ Kn, ushort* __restrict__ Vc)
{
    __shared__ __align__(16) ushort xF[64 * 264];   // 33.8 KB

    const int t    = threadIdx.x;
    const int b    = blockIdx.y;
    const int n0   = blockIdx.x * 64;
    const int lane = t & 63;
    const int w    = t >> 6;
    const int col  = lane & 15;
    const int quad = lane >> 4;

    // ---- stage x[b][0:256][n0:n0+64] -> xF[n][c] (bf16, transposed) ----
    {
        const int n4 = t & 15;        // n-quad: local n = n4*4 + jj
        const int cb = t >> 4;        // 0..15
#pragma unroll
        for (int r = 0; r < 4; ++r) {
            const int c0 = r * 64 + cb * 4;
            float4 L[4];
#pragma unroll
            for (int i = 0; i < 4; ++i)
                L[i] = *(const float4*)(x + ((size_t)b * kC + c0 + i) * kN + n0 + n4 * 4);
#pragma unroll
            for (int jj = 0; jj < 4; ++jj) {
                uint2 pk;
                pk.x = (uint)f2bf(((const float*)&L[0])[jj])
                     | ((uint)f2bf(((const float*)&L[1])[jj]) << 16);
                pk.y = (uint)f2bf(((const float*)&L[2])[jj])
                     | ((uint)f2bf(((const float*)&L[3])[jj]) << 16);
                *(uint2*)&xF[(n4 * 4 + jj) * 264 + c0] = pk;
            }
        }
    }
    __syncthreads();

    const int eh = w >> 1;            // e-half: rows eh*160 .. +159
    const int nh = w & 1;             // n-half: cols n0 + nh*32 .. +31

    float4v acc[10][2];
#pragma unroll
    for (int mt = 0; mt < 10; ++mt)
#pragma unroll
        for (int nt = 0; nt < 2; ++nt) acc[mt][nt] = float4v{0.f, 0.f, 0.f, 0.f};

    const ushort* Arow = Wb + ((size_t)(eh * 160 + col)) * kC;

#pragma unroll
    for (int kc = 0; kc < 8; ++kc) {
        short8 bf[2];
#pragma unroll
        for (int nt = 0; nt < 2; ++nt)
            bf[nt] = *(const short8*)&xF[(nh * 32 + nt * 16 + col) * 264 + kc * 32 + quad * 8];
#pragma unroll
        for (int mt = 0; mt < 10; ++mt) {
            const short8 af = *(const short8*)(Arow + (size_t)mt * 16 * kC + kc * 32 + quad * 8);
#pragma unroll
            for (int nt = 0; nt < 2; ++nt)
                acc[mt][nt] = __builtin_amdgcn_mfma_f32_16x16x32_bf16(af, bf[nt], acc[mt][nt], 0, 0, 0);
        }
    }

    // ---- epilogue: +bias, scatter to Vc / Qn / Kn ----
#pragma unroll
    for (int mt = 0; mt < 10; ++mt) {
        const int e_t = eh * 160 + mt * 16;
        const float4 b4 = *(const float4*)(bb + e_t + quad * 4);
#pragma unroll
        for (int nt = 0; nt < 2; ++nt) {
            const int n = n0 + nh * 32 + nt * 16 + col;
#pragma unroll
            for (int rr = 0; rr < 4; ++rr) {
                const int e = e_t + quad * 4 + rr;
                const float v = acc[mt][nt][rr] + ((const float*)&b4)[rr];
                if (e < 256)
                    Vc[((size_t)b * kC + e) * kN + n] = f2bf(v);
                else if (e < 288)
                    Qn[((size_t)b * kN + n) * kCQ + (e - 256)] = f2bf(v);
                else
                    Kn[((size_t)b * kN + n) * kCQ + (e - 288)] = f2bf(v);
            }
        }
    }
}

// ---------------------------------------------------------------------------
// MFMA flash attention (unchanged from R3). grid (8, 64), block 256 (4 waves).
// ---------------------------------------------------------------------------
__global__ __launch_bounds__(256, 2) void attn_kernel(
    const ushort* __restrict__ Qn, const ushort* __restrict__ Kn,
    const ushort* __restrict__ Vc,
    const float* __restrict__ x, const float* __restrict__ gptr,
    float* __restrict__ out)
{
    __shared__ __align__(16) ushort p_s[64 * 72];
    __shared__ float al_s[64];
    __shared__ float li_s[64];

    const int t    = threadIdx.x;
    const int b    = blockIdx.x;
    const int qb   = blockIdx.y;
    const int wq   = t >> 6;
    const int lane = t & 63;
    const int col  = lane & 15;
    const int quad = lane >> 4;
    const int cw   = wq * 64;

    const short8 qfrag = *(const short8*)(
        Qn + ((size_t)b * kN + qb * 64 + wq * 16 + col) * kCQ + quad * 8);

    float4v acc[4][4];
#pragma unroll
    for (int mt = 0; mt < 4; ++mt)
#pragma unroll
        for (int nt = 0; nt < 4; ++nt) acc[mt][nt] = float4v{0.f, 0.f, 0.f, 0.f};

    float m_i = -INFINITY, l_i = 0.f;

    const ushort* Kb = Kn + (size_t)b * kN * kCQ;
    const ushort* Vb = Vc + ((size_t)b * kC + cw) * kN;
    const float4v zero4 = {0.f, 0.f, 0.f, 0.f};

    short8 kf[4];
#pragma unroll
    for (int mt = 0; mt < 4; ++mt)
        kf[mt] = *(const short8*)(Kb + (size_t)(mt * 16 + col) * kCQ + quad * 8);

    for (int tile = 0; tile < kN / 64; ++tile) {
        const int k0 = tile * 64;

        float4v s[4];
#pragma unroll
        for (int mt = 0; mt < 4; ++mt)
            s[mt] = __builtin_amdgcn_mfma_f32_16x16x32_bf16(kf[mt], qfrag, zero4, 0, 0, 0);

        short8 vf[2][4];
#pragma unroll
        for (int ks = 0; ks < 2; ++ks)
#pragma unroll
            for (int mt = 0; mt < 4; ++mt)
                vf[ks][mt] = *(const short8*)(
                    Vb + (size_t)(mt * 16 + col) * kN + k0 + ks * 32 + quad * 8);
        const int k0n = (tile + 1 < kN / 64) ? (tile + 1) * 64 : 0;
#pragma unroll
        for (int mt = 0; mt < 4; ++mt)
            kf[mt] = *(const short8*)(
                Kb + (size_t)(k0n + mt * 16 + col) * kCQ + quad * 8);

        float mx = -INFINITY;
#pragma unroll
        for (int mt = 0; mt < 4; ++mt)
#pragma unroll
            for (int r = 0; r < 4; ++r) mx = fmaxf(mx, s[mt][r]);
        mx = fmaxf(mx, __shfl_xor(mx, 16));
        mx = fmaxf(mx, __shfl_xor(mx, 32));
        const float mnew  = fmaxf(m_i, mx);
        const float alpha = exp2f(m_i - mnew);
        float lsum = 0.f;
#pragma unroll
        for (int mt = 0; mt < 4; ++mt) {
            float p0 = exp2f(s[mt][0] - mnew);
            float p1 = exp2f(s[mt][1] - mnew);
            float p2 = exp2f(s[mt][2] - mnew);
            float p3 = exp2f(s[mt][3] - mnew);
            lsum += (p0 + p1) + (p2 + p3);
            uint2 pk;
            pk.x = (uint)f2bf(p0) | ((uint)f2bf(p1) << 16);
            pk.y = (uint)f2bf(p2) | ((uint)f2bf(p3) << 16);
            *(uint2*)&p_s[(wq * 16 + col) * 72 + mt * 16 + quad * 4] = pk;
        }
        lsum += __shfl_xor(lsum, 16);
        lsum += __shfl_xor(lsum, 32);
        l_i = l_i * alpha + lsum;
        m_i = mnew;
        if (quad == 0) al_s[wq * 16 + col] = alpha;
        __syncthreads();

        float al[4];
#pragma unroll
        for (int nt = 0; nt < 4; ++nt) al[nt] = al_s[nt * 16 + col];
#pragma unroll
        for (int mt = 0; mt < 4; ++mt)
#pragma unroll
            for (int nt = 0; nt < 4; ++nt) acc[mt][nt] *= al[nt];

#pragma unroll
        for (int ks = 0; ks < 2; ++ks) {
            short8 pf[4];
#pragma unroll
            for (int nt = 0; nt < 4; ++nt)
                pf[nt] = *(const short8*)&p_s[(nt * 16 + col) * 72 + ks * 32 + quad * 8];
#pragma unroll
            for (int mt = 0; mt < 4; ++mt)
#pragma unroll
                for (int nt = 0; nt < 4; ++nt)
                    acc[mt][nt] = __builtin_amdgcn_mfma_f32_16x16x32_bf16(
                        vf[ks][mt], pf[nt], acc[mt][nt], 0, 0, 0);
        }
        __syncthreads();
    }

    if (quad == 0) li_s[wq * 16 + col] = l_i;
    __syncthreads();
    const float g = gptr[0];
    float linv[4];
#pragma unroll
    for (int nt = 0; nt < 4; ++nt) linv[nt] = 1.0f / li_s[nt * 16 + col];

#pragma unroll
    for (int mt = 0; mt < 4; ++mt) {
#pragma unroll
        for (int nt = 0; nt < 4; ++nt) {
            const int n = qb * 64 + nt * 16 + col;
#pragma unroll
            for (int r = 0; r < 4; ++r) {
                const int c = cw + mt * 16 + quad * 4 + r;
                const size_t idx = ((size_t)b * kC + c) * kN + n;
                out[idx] = g * (acc[mt][nt][r] * linv[nt]) + x[idx];
            }
        }
    }
}

extern "C" void kernel_launch(void* const* d_in, const int* in_sizes, int n_in,
                              void* d_out, int out_size, void* d_ws, size_t ws_size,
                              hipStream_t stream)
{
    const float* x  = (const float*)d_in[0];
    const float* wq = (const float*)d_in[1];
    const float* bq = (const float*)d_in[2];
    const float* wk = (const float*)d_in[3];
    const float* bk = (const float*)d_in[4];
    const float* wv = (const float*)d_in[5];
    const float* bv = (const float*)d_in[6];
    const float* gm = (const float*)d_in[7];
    float* out = (float*)d_out;

    ushort* Qn = (ushort*)d_ws;                         // [8][4096][32] bf16, 2 MB
    ushort* Kn = Qn + (size_t)kB * kN * kCQ;            // [8][4096][32] bf16, 2 MB
    ushort* Vc = Kn + (size_t)kB * kN * kCQ;            // [8][256][4096] bf16, 16 MB
    ushort* Wb = Vc + (size_t)kB * kC * kN;             // [320][256] bf16, 160 KB
    float*  bb = (float*)(Wb + (size_t)kE * kC);        // [320] f32

    prep_kernel<<<dim3(kE), 256, 0, stream>>>(wq, bq, wk, bk, wv, bv, Wb, bb);
    proj_kernel<<<dim3(64, 8), 256, 0, stream>>>(x, Wb, bb, Qn, Kn, Vc);
    attn_kernel<<<dim3(8, 64), 256, 0, stream>>>(Qn, Kn, Vc, x, gm, out);
}